// Round 1
// baseline (58.251 us; speedup 1.0000x reference)
//
#include <hip/hip_runtime.h>

#define BB 32
#define NN 1024
#define TT 4096
#define CC 384
#define C4 (CC/4)   // 96 float4 per row

// Kernel A: per-batch inclusive scan of clamped durations + scatter idx table.
// idx_ws[b*TT + t] = n for t in [cum[n-1], cum[n]); stays -1 for t >= total.
__global__ void lr_scan_scatter(const int* __restrict__ duration,
                                int* __restrict__ idx_ws) {
    __shared__ int s[NN];
    const int b = blockIdx.x;
    const int n = threadIdx.x;
    int d = duration[b * NN + n];
    if (d < 0) d = 0;
    s[n] = d;
    __syncthreads();
    // Hillis-Steele inclusive scan over 1024 elements (10 steps)
    #pragma unroll
    for (int off = 1; off < NN; off <<= 1) {
        int v = (n >= off) ? s[n - off] : 0;
        __syncthreads();
        s[n] += v;
        __syncthreads();
    }
    int end = s[n];          // cum[n]
    int start = end - d;     // cum[n-1]
    if (start < 0) start = 0;
    if (end > TT) end = TT;
    int* row = idx_ws + (size_t)b * TT;
    for (int t = start; t < end; ++t) row[t] = n;
}

// Kernel B: gather x rows into out, zeros where idx == -1. float4 vectorized.
__global__ void lr_gather(const float4* __restrict__ x4,
                          const int* __restrict__ idx_ws,
                          float4* __restrict__ out4) {
    const unsigned total = BB * TT * C4;
    unsigned g = blockIdx.x * blockDim.x + threadIdx.x;
    const unsigned stride = gridDim.x * blockDim.x;
    for (; g < total; g += stride) {
        unsigned row = g / C4;            // magic-mul, compiler handles
        unsigned lane = g - row * C4;
        int id = idx_ws[row];
        float4 v = make_float4(0.f, 0.f, 0.f, 0.f);
        if (id >= 0) {
            unsigned b = row / TT;        // row >> 12
            v = x4[((size_t)b * NN + (unsigned)id) * C4 + lane];
        }
        out4[g] = v;
    }
}

// Kernel C: mel_mask as float 0/1 (t < total  <=>  idx_ws set)
__global__ void lr_mask(const int* __restrict__ idx_ws,
                        float* __restrict__ mask) {
    unsigned g = blockIdx.x * blockDim.x + threadIdx.x;
    if (g < BB * TT) mask[g] = (idx_ws[g] >= 0) ? 1.0f : 0.0f;
}

extern "C" void kernel_launch(void* const* d_in, const int* in_sizes, int n_in,
                              void* d_out, int out_size, void* d_ws, size_t ws_size,
                              hipStream_t stream) {
    const float* x        = (const float*)d_in[0];
    const int*   duration = (const int*)d_in[1];
    // d_in[2] = max_length (4096) — fixed problem size, baked into TT.

    int*   idx_ws = (int*)d_ws;                       // BB*TT ints = 512 KiB
    float* out    = (float*)d_out;                    // BB*TT*CC floats
    float* mask   = out + (size_t)BB * TT * CC;       // BB*TT floats

    // -1 sentinel for "past total length" rows
    hipMemsetAsync(idx_ws, 0xFF, (size_t)BB * TT * sizeof(int), stream);

    lr_scan_scatter<<<BB, NN, 0, stream>>>(duration, idx_ws);

    lr_gather<<<2048, 256, 0, stream>>>((const float4*)x, idx_ws, (float4*)out);

    lr_mask<<<(BB * TT) / 256, 256, 0, stream>>>(idx_ws, mask);
}

// Round 2
// 53.460 us; speedup vs baseline: 1.0896x; 1.0896x over previous
//
#include <hip/hip_runtime.h>

#define BB 32
#define NN 1024
#define TT 4096
#define CC 384
#define C4 (CC/4)   // 96 float4 per row

// Kernel A: per-batch inclusive scan of clamped durations, scatter idx table,
// and fill the tail [total, TT) with -1 (replaces the memset dispatch).
__global__ void lr_scan_scatter(const int* __restrict__ duration,
                                int* __restrict__ idx_ws) {
    __shared__ int s[NN];
    const int b = blockIdx.x;
    const int n = threadIdx.x;
    int d = duration[b * NN + n];
    if (d < 0) d = 0;
    s[n] = d;
    __syncthreads();
    // Hillis-Steele inclusive scan over 1024 elements (10 steps)
    #pragma unroll
    for (int off = 1; off < NN; off <<= 1) {
        int v = (n >= off) ? s[n - off] : 0;
        __syncthreads();
        s[n] += v;
        __syncthreads();
    }
    int end = s[n];          // cum[n]
    int start = end - d;     // cum[n-1]
    if (start < 0) start = 0;
    if (end > TT) end = TT;
    int total = s[NN - 1];
    if (total > TT) total = TT;

    int* row = idx_ws + (size_t)b * TT;
    for (int t = start; t < end; ++t) row[t] = n;
    // cooperative tail fill: rows past total get the -1 sentinel
    for (int t = total + n; t < TT; t += NN) row[t] = -1;
}

// Kernel B: gather x rows into out (zeros where idx == -1), fused mask write.
__global__ void lr_gather(const float4* __restrict__ x4,
                          const int* __restrict__ idx_ws,
                          float4* __restrict__ out4,
                          float* __restrict__ mask) {
    const unsigned total = BB * TT * C4;
    unsigned g = blockIdx.x * blockDim.x + threadIdx.x;
    const unsigned stride = gridDim.x * blockDim.x;
    for (; g < total; g += stride) {
        unsigned row = g / C4;            // compiler emits magic-mul
        unsigned lane = g - row * C4;
        int id = idx_ws[row];
        float4 v = make_float4(0.f, 0.f, 0.f, 0.f);
        if (id >= 0) {
            unsigned b = row >> 12;       // row / TT
            v = x4[((size_t)b * NN + (unsigned)id) * C4 + lane];
        }
        out4[g] = v;
        if (lane == 0) mask[row] = (id >= 0) ? 1.0f : 0.0f;
    }
}

extern "C" void kernel_launch(void* const* d_in, const int* in_sizes, int n_in,
                              void* d_out, int out_size, void* d_ws, size_t ws_size,
                              hipStream_t stream) {
    const float* x        = (const float*)d_in[0];
    const int*   duration = (const int*)d_in[1];
    // d_in[2] = max_length (4096) — fixed problem size, baked into TT.

    int*   idx_ws = (int*)d_ws;                       // BB*TT ints = 512 KiB
    float* out    = (float*)d_out;                    // BB*TT*CC floats
    float* mask   = out + (size_t)BB * TT * CC;       // BB*TT floats

    lr_scan_scatter<<<BB, NN, 0, stream>>>(duration, idx_ws);

    lr_gather<<<2048, 256, 0, stream>>>((const float4*)x, idx_ws,
                                        (float4*)out, mask);
}

// Round 3
// 52.812 us; speedup vs baseline: 1.1030x; 1.0123x over previous
//
#include <hip/hip_runtime.h>

#define BB 32
#define NN 1024
#define TT 4096
#define CC 384
#define C4 (CC/4)   // 96 float4 per row

typedef float f4v __attribute__((ext_vector_type(4)));

// Kernel A: per-batch scan (wave shfl + 1 barrier), scatter idx table,
// -1 tail fill, and mask write.
__global__ void lr_scan_scatter(const int* __restrict__ duration,
                                int* __restrict__ idx_ws,
                                float* __restrict__ mask) {
    __shared__ int wsum[16];
    const int b = blockIdx.x;
    const int n = threadIdx.x;        // 0..1023
    const int lane = n & 63;
    const int wid = n >> 6;           // 0..15

    int d = duration[b * NN + n];
    if (d < 0) d = 0;

    // wave-level inclusive scan (64 lanes, 6 shfl steps, no barriers)
    int v = d;
    #pragma unroll
    for (int off = 1; off < 64; off <<= 1) {
        int t = __shfl_up(v, off, 64);
        if (lane >= off) v += t;
    }
    if (lane == 63) wsum[wid] = v;
    __syncthreads();

    // per-thread: offset of my wave + batch total (LDS broadcast reads)
    int woff = 0, tot = 0;
    #pragma unroll
    for (int w = 0; w < 16; ++w) {
        int s = wsum[w];
        tot += s;
        if (w < wid) woff += s;
    }

    int end = v + woff;               // cum[n]
    int start = end - d;              // cum[n-1]
    if (start > TT) start = TT;
    if (end > TT) end = TT;
    int total = tot > TT ? TT : tot;

    int* row = idx_ws + (size_t)b * TT;
    for (int t = start; t < end; ++t) row[t] = n;
    // tail sentinel for rows past total
    for (int t = total + n; t < TT; t += NN) row[t] = -1;
    // mask (coalesced, 4 iters/thread)
    float* m = mask + (size_t)b * TT;
    #pragma unroll
    for (int t = n; t < TT; t += NN) m[t] = (t < total) ? 1.0f : 0.0f;
}

// Kernel B: pure gather, non-temporal float4 stores.
__global__ void lr_gather(const float4* __restrict__ x4,
                          const int* __restrict__ idx_ws,
                          float4* __restrict__ out4) {
    const unsigned total = BB * TT * C4;
    unsigned g = blockIdx.x * blockDim.x + threadIdx.x;
    const unsigned stride = gridDim.x * blockDim.x;
    for (; g < total; g += stride) {
        unsigned row = g / C4;            // magic-mul
        unsigned lane = g - row * C4;
        int id = idx_ws[row];
        float4 v = make_float4(0.f, 0.f, 0.f, 0.f);
        if (id >= 0) {
            unsigned b = row >> 12;       // row / TT
            v = x4[((size_t)b * NN + (unsigned)id) * C4 + lane];
        }
        __builtin_nontemporal_store(*(const f4v*)&v, (f4v*)&out4[g]);
    }
}

extern "C" void kernel_launch(void* const* d_in, const int* in_sizes, int n_in,
                              void* d_out, int out_size, void* d_ws, size_t ws_size,
                              hipStream_t stream) {
    const float* x        = (const float*)d_in[0];
    const int*   duration = (const int*)d_in[1];
    // d_in[2] = max_length (4096) — fixed, baked into TT.

    int*   idx_ws = (int*)d_ws;                       // BB*TT ints = 512 KiB
    float* out    = (float*)d_out;                    // BB*TT*CC floats
    float* mask   = out + (size_t)BB * TT * CC;       // BB*TT floats

    lr_scan_scatter<<<BB, NN, 0, stream>>>(duration, idx_ws, mask);

    lr_gather<<<2048, 256, 0, stream>>>((const float4*)x, idx_ws, (float4*)out);
}

// Round 4
// 46.777 us; speedup vs baseline: 1.2453x; 1.1290x over previous
//
#include <hip/hip_runtime.h>

#define BB 32
#define NN 1024
#define TT 4096
#define CC 384
#define C4 (CC/4)    // 96 float4 per row
#define RPB 64       // output rows per block
#define BPB (TT/RPB) // 64 blocks per batch
#define THR 256

typedef float f4v __attribute__((ext_vector_type(4)));

// One fused kernel: per-block redundant scan of its batch's durations (4 KiB),
// per-row binary search (searchsorted right), streamed gather + mask write.
__global__ __launch_bounds__(THR) void lr_fused(const int* __restrict__ duration,
                                                const float4* __restrict__ x4,
                                                float4* __restrict__ out4,
                                                float* __restrict__ mask) {
    __shared__ int cum[NN];     // inclusive cumsum of clamped durations
    __shared__ int wtot[4];
    __shared__ int ridx[RPB];

    const int b    = blockIdx.x / BPB;
    const int rblk = blockIdx.x % BPB;
    const int tid  = threadIdx.x;
    const int lane = tid & 63;
    const int wid  = tid >> 6;

    // ---- load 4 durations/thread, clamp, local prefix
    const int4 dv = ((const int4*)(duration + b * NN))[tid];
    int d0 = max(dv.x, 0), d1 = max(dv.y, 0), d2 = max(dv.z, 0), d3 = max(dv.w, 0);
    int p0 = d0, p1 = p0 + d1, p2 = p1 + d2, p3 = p2 + d3;

    // wave inclusive scan of thread sums (6 shfl steps)
    int v = p3;
    #pragma unroll
    for (int off = 1; off < 64; off <<= 1) {
        int t = __shfl_up(v, off, 64);
        if (lane >= off) v += t;
    }
    if (lane == 63) wtot[wid] = v;
    __syncthreads();
    int woff = 0;
    #pragma unroll
    for (int w = 0; w < 4; ++w)
        if (w < wid) woff += wtot[w];
    int excl = woff + (v - p3);          // exclusive prefix of this thread's 4
    int4 cv = make_int4(excl + p0, excl + p1, excl + p2, excl + p3);
    ((int4*)cum)[tid] = cv;
    __syncthreads();

    const int total = cum[NN - 1];

    // ---- per-row source index via binary search (first 64 threads)
    if (tid < RPB) {
        int row = rblk * RPB + tid;      // t in [0, TT)
        int id = -1;
        if (row < total) {
            // searchsorted(cum, row, 'right'): first n with cum[n] > row.
            // row < total == cum[NN-1] guarantees answer in [0, NN-1].
            int lo = 0, hi = NN - 1;
            #pragma unroll
            for (int it = 0; it < 10; ++it) {
                int mid = (lo + hi) >> 1;
                if (cum[mid] > row) hi = mid; else lo = mid + 1;
            }
            id = hi;
        }
        ridx[tid] = id;
        mask[(size_t)b * TT + row] = (id >= 0) ? 1.0f : 0.0f;
    }
    __syncthreads();

    // ---- streamed gather: 64 rows x 96 float4 = 24 iters/thread
    const float4* xb = x4 + (size_t)b * NN * C4;
    float4* ob = out4 + ((size_t)b * TT + (size_t)rblk * RPB) * C4;
    #pragma unroll
    for (int it = 0; it < RPB * C4 / THR; ++it) {
        int i = it * THR + tid;
        int r = i / C4;                  // magic-mul
        int lane2 = i - r * C4;
        int id = ridx[r];
        float4 vv = make_float4(0.f, 0.f, 0.f, 0.f);
        if (id >= 0) vv = xb[(size_t)id * C4 + lane2];
        __builtin_nontemporal_store(*(const f4v*)&vv, (f4v*)&ob[i]);
    }
}

extern "C" void kernel_launch(void* const* d_in, const int* in_sizes, int n_in,
                              void* d_out, int out_size, void* d_ws, size_t ws_size,
                              hipStream_t stream) {
    const float* x        = (const float*)d_in[0];
    const int*   duration = (const int*)d_in[1];
    // d_in[2] = max_length (4096) — fixed, baked into TT.

    float* out  = (float*)d_out;                    // BB*TT*CC floats
    float* mask = out + (size_t)BB * TT * CC;       // BB*TT floats

    lr_fused<<<BB * BPB, THR, 0, stream>>>(duration, (const float4*)x,
                                           (float4*)out, mask);
}